// Round 11
// baseline (358.708 us; speedup 1.0000x reference)
//
#include <hip/hip_runtime.h>
#include <math.h>

#define N_NODES 100000
#define N_EDGES 1600000
#define NBUCK 391          // ceil(100000 / 256)
#define BSTRIDE 4608       // bucket slack stride: mean 4096 + 8 sigma

typedef __attribute__((ext_vector_type(8))) _Float16 h8v;
typedef __attribute__((ext_vector_type(4))) float f32x4;
typedef __attribute__((ext_vector_type(2))) int i32x2;

#define GEMM_GRID 625
#define NTILES 3125

// ---------------- bpart + misc tail ----------------
// Blocks 0..390: edge partition into 391 dst-buckets (round-0 proven form).
// Blocks 391..478: weight prep for W2 (128 cols) + W3 (48, zero-padded).
// Block 479: zero sentinel rows of bufA/bufB/zbuf.
// (bcnt zeroed by hipMemsetAsync before this launch.)

__launch_bounds__(256)
__global__ void k_bpart(const int* __restrict__ srcv, const int* __restrict__ dstv,
                        int* __restrict__ bcnt, unsigned int* __restrict__ ebuf,
                        const float* __restrict__ W2, const float* __restrict__ W3,
                        _Float16* __restrict__ Wt,
                        _Float16* __restrict__ bufA, _Float16* __restrict__ bufB,
                        _Float16* __restrict__ zbuf) {
    const int tid = threadIdx.x;
    const int bid = blockIdx.x;

    if (bid >= 391) {
        if (bid == 479) {
            if (tid < 128) {
                bufA[(size_t)N_NODES * 128 + tid] = (_Float16)0.f;
                bufB[(size_t)N_NODES * 128 + tid] = (_Float16)0.f;
            }
            if (tid < 64)  zbuf[(size_t)N_NODES * 64 + tid] = (_Float16)0.f;
            return;
        }
        // weight prep: 176*128 = 22528 elements over 88 blocks (exact)
        int idx = (bid - 391) * 256 + tid;
        if (idx >= 176 * 128) return;
        int n = idx / 128, k = idx % 128;
        _Float16 *ph, *pl;
        float v;
        if (n < 128) {
            v = W2[k * 128 + n];
            ph = Wt + 2 * 128 * 128; pl = Wt + 3 * 128 * 128;
        } else {
            int nloc = n - 128;
            v = (nloc < 40) ? W3[k * 40 + nloc] : 0.f;
            ph = Wt + 4 * 128 * 128; pl = Wt + 4 * 128 * 128 + 48 * 128;
            n = nloc;
        }
        _Float16 hi = (_Float16)v;
        _Float16 lo = (_Float16)(v - (float)hi);
        ph[n * 128 + k] = hi;
        pl[n * 128 + k] = lo;
        return;
    }

    // ---- bpart ----
    __shared__ int hist[NBUCK];
    __shared__ int cur[NBUCK];
    for (int t = tid; t < NBUCK; t += 256) hist[t] = 0;
    __syncthreads();
    const int base = bid * 4096;
#pragma unroll
    for (int i = 0; i < 16; i++) {
        int e = base + i * 256 + tid;
        if (e < N_EDGES) atomicAdd(&hist[dstv[e] >> 8], 1);
    }
    __syncthreads();
    for (int t = tid; t < NBUCK; t += 256)
        if (hist[t]) cur[t] = t * BSTRIDE + atomicAdd(&bcnt[t], hist[t]);
    __syncthreads();
#pragma unroll
    for (int i = 0; i < 16; i++) {
        int e = base + i * 256 + tid;
        if (e < N_EDGES) {
            int d = dstv[e];
            int p = atomicAdd(&cur[d >> 8], 1);
            ebuf[p] = ((unsigned int)srcv[e] << 8) | (unsigned int)(d & 255);
        }
    }
}

// ---------------- CSR finalize + block-local L1 GEMM ----------------
// Block b: (1) builds CSR rows + dinv for nodes b*256..b*256+255 (dinv kept
// in LDS sdv[]); (2) runs the layer-1 GEMM for those SAME 256 rows with the
// dinv epilogue from LDS — dependency is block-local, no grid sync needed.
// Phases are sequential and homogeneous across blocks (no co-residency mix).

__launch_bounds__(256)
__global__ void k_bucket(const unsigned int* __restrict__ ebuf, const int* __restrict__ bcnt,
                         i32x2* __restrict__ rowse, float* __restrict__ dinv,
                         int* __restrict__ colidx,
                         const float* __restrict__ x, const float* __restrict__ W1,
                         _Float16* __restrict__ bufA) {
    __shared__ int cnt[256];
    __shared__ int s[256];
    __shared__ int cur[256];
    __shared__ float sdv[256];
    const int tid = threadIdx.x;
    const int b = blockIdx.x;
    const int e0 = b * BSTRIDE;
    const int e1 = e0 + bcnt[b];
    cnt[tid] = 0;
    __syncthreads();
    for (int e = e0 + tid; e < e1; e += 256) atomicAdd(&cnt[ebuf[e] & 255u], 1);
    __syncthreads();
    int v = cnt[tid];
    int x0 = v;
    s[tid] = x0;
    __syncthreads();
    for (int d = 1; d < 256; d <<= 1) {
        int t = (tid >= d) ? s[tid - d] : 0;
        __syncthreads();
        x0 += t;
        s[tid] = x0;
        __syncthreads();
    }
    int start = e0 + x0 - v;
    int node = b * 256 + tid;
    float dvv = rsqrtf((float)(v + 1));
    sdv[tid] = dvv;
    if (node < N_NODES) {
        i32x2 se;
        se.x = start;
        se.y = start + v;
        rowse[node] = se;
        dinv[node] = dvv;  // +1 self-loop (global copy for fused epilogues)
    }
    cur[tid] = start;
    __syncthreads();
    for (int e = e0 + tid; e < e1; e += 256) {
        unsigned int sd = ebuf[e];
        int pos = atomicAdd(&cur[sd & 255u], 1);
        colidx[pos] = (int)(sd >> 8);
    }

    // ---- block-local layer-1 GEMM: bufA[r] = dinv[r] * (x @ W1)[r], r in this
    // block's 256 rows (8 tiles of 32). sdv was synced before the scatter loop.
    const int lane = tid & 63;
    const int wi = tid >> 6;
    const int nb = wi * 32;
    const int nn = lane & 15;
    const int quad = lane >> 4;
    const int kq = quad * 8;

    h8v bh[4][2], bl[4][2];
#pragma unroll
    for (int c = 0; c < 4; c++)
#pragma unroll
        for (int t = 0; t < 2; t++) {
#pragma unroll
            for (int j = 0; j < 8; j++) {
                float w = W1[(c * 32 + kq + j) * 128 + nb + t * 16 + nn];
                _Float16 hi = (_Float16)w;
                bh[c][t][j] = hi;
                bl[c][t][j] = (_Float16)(w - (float)hi);
            }
        }

#pragma unroll
    for (int tile = 0; tile < 8; tile++) {
        const int r0 = b * 256 + tile * 32;
        if (r0 >= N_NODES) break;
        f32x4 acc[2][2] = {};
#pragma unroll
        for (int c = 0; c < 4; c++) {
            h8v a[2];
#pragma unroll
            for (int m = 0; m < 2; m++) {
                int rl = r0 + m * 16 + nn;
                rl = (rl < N_NODES) ? rl : (N_NODES - 1);  // clamp OOB tail reads
                const float* p = x + (size_t)rl * 128 + c * 32 + kq;
                float4 p0 = *(const float4*)p;
                float4 p1 = *(const float4*)(p + 4);
                h8v av = {(_Float16)p0.x, (_Float16)p0.y, (_Float16)p0.z, (_Float16)p0.w,
                          (_Float16)p1.x, (_Float16)p1.y, (_Float16)p1.z, (_Float16)p1.w};
                a[m] = av;
            }
#pragma unroll
            for (int m = 0; m < 2; m++)
#pragma unroll
                for (int t = 0; t < 2; t++) {
                    acc[m][t] = __builtin_amdgcn_mfma_f32_16x16x32_f16(a[m], bh[c][t], acc[m][t], 0, 0, 0);
                    acc[m][t] = __builtin_amdgcn_mfma_f32_16x16x32_f16(a[m], bl[c][t], acc[m][t], 0, 0, 0);
                }
        }
#pragma unroll
        for (int m = 0; m < 2; m++)
#pragma unroll
            for (int reg = 0; reg < 4; reg++) {
                int r = r0 + m * 16 + quad * 4 + reg;
                if (r < N_NODES) {
                    float dv = sdv[r - b * 256];
#pragma unroll
                    for (int t = 0; t < 2; t++)
                        bufA[(size_t)r * 128 + nb + t * 16 + nn] = (_Float16)(acc[m][t][reg] * dv);
                }
            }
    }
}

// ---------------- Fused aggregation + GEMM, 16-row tiles (R10 verified form) ----------------

__launch_bounds__(256)
__global__ void k_fused128(const _Float16* __restrict__ hp, const i32x2* __restrict__ rowse,
                           const int* __restrict__ colidx, const float* __restrict__ bias,
                           const float* __restrict__ dinv,
                           const _Float16* __restrict__ Wthi, const _Float16* __restrict__ Wtlo,
                           _Float16* __restrict__ out) {
    __shared__ __align__(16) _Float16 As[16 * 128];
    const int lane = threadIdx.x & 63;
    const int wi = threadIdx.x >> 6;
    const int nn = lane & 15;
    const int quad = lane >> 4;
    const int r0 = blockIdx.x * 16;

    // ---- phase A ----
    {
        const int rl = wi * 4 + quad;
        const int r = r0 + rl;
        const i32x2 se = rowse[r];
        const int deg = se.y - se.x;
        int m = deg;
        m = max(m, __shfl_xor(m, 16));
        m = max(m, __shfl_xor(m, 32));
        const _Float16* hpc = hp + nn * 8;
        h8v acc = {};
        for (int it = 0; it < m; it += 4) {
            int i0 = se.x + it;
            int s0 = colidx[i0];
            int s1 = colidx[i0 + 1];
            int s2 = colidx[i0 + 2];
            int s3 = colidx[i0 + 3];
            s0 = (it < deg) ? s0 : N_NODES;
            s1 = (it + 1 < deg) ? s1 : N_NODES;
            s2 = (it + 2 < deg) ? s2 : N_NODES;
            s3 = (it + 3 < deg) ? s3 : N_NODES;
            h8v v0 = *(const h8v*)(hpc + (size_t)s0 * 128);
            h8v v1 = *(const h8v*)(hpc + (size_t)s1 * 128);
            h8v v2 = *(const h8v*)(hpc + (size_t)s2 * 128);
            h8v v3 = *(const h8v*)(hpc + (size_t)s3 * 128);
            acc += v0;
            acc += v1;
            acc += v2;
            acc += v3;
        }
        h8v sv = *(const h8v*)(hpc + (size_t)r * 128);  // self-loop (g[r])
        float dv = rsqrtf((float)(deg + 1));
        const float* bp = bias + nn * 8;
        float4 b0 = *(const float4*)bp;
        float4 b1 = *(const float4*)(bp + 4);
        float bb[8] = {b0.x, b0.y, b0.z, b0.w, b1.x, b1.y, b1.z, b1.w};
        h8v o;
#pragma unroll
        for (int j = 0; j < 8; j++) {
            float sx = (float)acc[j] + (float)sv[j];
            o[j] = (_Float16)fmaxf(fmaf(dv, sx, bb[j]), 0.f);
        }
        *(h8v*)(As + rl * 128 + ((nn ^ rl) * 8)) = o;
    }
    __syncthreads();

    // ---- phase B: 16x128 tile @ W (wave wi -> cols wi*32..+31), out *= dinv[r] ----
    const int nb = wi * 32;
    const int kq = quad * 8;
    f32x4 acc2[2] = {};
#pragma unroll
    for (int c = 0; c < 4; c++) {
        int ch = (c * 4 + quad) ^ nn;
        h8v a = *(const h8v*)(As + nn * 128 + ch * 8);
#pragma unroll
        for (int t = 0; t < 2; t++) {
            int off = (nb + t * 16 + nn) * 128 + c * 32 + kq;
            h8v bhv = *(const h8v*)(Wthi + off);
            h8v blv = *(const h8v*)(Wtlo + off);
            acc2[t] = __builtin_amdgcn_mfma_f32_16x16x32_f16(a, bhv, acc2[t], 0, 0, 0);
            acc2[t] = __builtin_amdgcn_mfma_f32_16x16x32_f16(a, blv, acc2[t], 0, 0, 0);
        }
    }
#pragma unroll
    for (int reg = 0; reg < 4; reg++) {
        int r = r0 + quad * 4 + reg;
        float dr = dinv[r];
#pragma unroll
        for (int t = 0; t < 2; t++)
            out[(size_t)r * 128 + nb + t * 16 + nn] = (_Float16)(acc2[t][reg] * dr);
    }
}

// Fused aggregation + layer-3 GEMM (48 cols) into [N+1][64]-stride buffer.
__launch_bounds__(256)
__global__ void k_fused40(const _Float16* __restrict__ hp, const i32x2* __restrict__ rowse,
                          const int* __restrict__ colidx, const float* __restrict__ bias,
                          const float* __restrict__ dinv,
                          const _Float16* __restrict__ Wthi, const _Float16* __restrict__ Wtlo,
                          _Float16* __restrict__ out) {
    __shared__ __align__(16) _Float16 As[16 * 128];
    const int lane = threadIdx.x & 63;
    const int wi = threadIdx.x >> 6;
    const int nn = lane & 15;
    const int quad = lane >> 4;
    const int r0 = blockIdx.x * 16;

    // ---- phase A ----
    {
        const int rl = wi * 4 + quad;
        const int r = r0 + rl;
        const i32x2 se = rowse[r];
        const int deg = se.y - se.x;
        int m = deg;
        m = max(m, __shfl_xor(m, 16));
        m = max(m, __shfl_xor(m, 32));
        const _Float16* hpc = hp + nn * 8;
        h8v acc = {};
        for (int it = 0; it < m; it += 4) {
            int i0 = se.x + it;
            int s0 = colidx[i0];
            int s1 = colidx[i0 + 1];
            int s2 = colidx[i0 + 2];
            int s3 = colidx[i0 + 3];
            s0 = (it < deg) ? s0 : N_NODES;
            s1 = (it + 1 < deg) ? s1 : N_NODES;
            s2 = (it + 2 < deg) ? s2 : N_NODES;
            s3 = (it + 3 < deg) ? s3 : N_NODES;
            h8v v0 = *(const h8v*)(hpc + (size_t)s0 * 128);
            h8v v1 = *(const h8v*)(hpc + (size_t)s1 * 128);
            h8v v2 = *(const h8v*)(hpc + (size_t)s2 * 128);
            h8v v3 = *(const h8v*)(hpc + (size_t)s3 * 128);
            acc += v0;
            acc += v1;
            acc += v2;
            acc += v3;
        }
        h8v sv = *(const h8v*)(hpc + (size_t)r * 128);
        float dv = rsqrtf((float)(deg + 1));
        const float* bp = bias + nn * 8;
        float4 b0 = *(const float4*)bp;
        float4 b1 = *(const float4*)(bp + 4);
        float bb[8] = {b0.x, b0.y, b0.z, b0.w, b1.x, b1.y, b1.z, b1.w};
        h8v o;
#pragma unroll
        for (int j = 0; j < 8; j++) {
            float sx = (float)acc[j] + (float)sv[j];
            o[j] = (_Float16)fmaxf(fmaf(dv, sx, bb[j]), 0.f);
        }
        *(h8v*)(As + rl * 128 + ((nn ^ rl) * 8)) = o;
    }
    __syncthreads();

    // ---- phase B: 16x128 tile @ W3 (waves 0..2 -> cols wi*16..+15), out *= dinv[r] ----
    if (wi < 3) {
        const int kq = quad * 8;
        f32x4 acc2 = {};
#pragma unroll
        for (int c = 0; c < 4; c++) {
            int ch = (c * 4 + quad) ^ nn;
            h8v a = *(const h8v*)(As + nn * 128 + ch * 8);
            int off = (wi * 16 + nn) * 128 + c * 32 + kq;
            h8v bhv = *(const h8v*)(Wthi + off);
            h8v blv = *(const h8v*)(Wtlo + off);
            acc2 = __builtin_amdgcn_mfma_f32_16x16x32_f16(a, bhv, acc2, 0, 0, 0);
            acc2 = __builtin_amdgcn_mfma_f32_16x16x32_f16(a, blv, acc2, 0, 0, 0);
        }
#pragma unroll
        for (int reg = 0; reg < 4; reg++) {
            int r = r0 + quad * 4 + reg;
            float dr = dinv[r];
            out[(size_t)r * 64 + wi * 16 + nn] = (_Float16)(acc2[reg] * dr);
        }
    }
}

// ---------------- Final aggregation (64-stride rows) + fused log_softmax ----------------

__launch_bounds__(256)
__global__ void k_agg_out(const _Float16* __restrict__ hp, const i32x2* __restrict__ rowse,
                          const int* __restrict__ colidx, float* __restrict__ out) {
    const int lane = threadIdx.x & 63;
    const int wid = (blockIdx.x * blockDim.x + threadIdx.x) >> 6;
    const int rs = lane >> 3;   // row slot 0..7
    const int cp = lane & 7;    // 16B col part
    const int r = wid * 8 + rs;

    const i32x2 se = rowse[r];
    const int deg = se.y - se.x;
    int m = deg;
    m = max(m, __shfl_xor(m, 8));
    m = max(m, __shfl_xor(m, 16));
    m = max(m, __shfl_xor(m, 32));

    const _Float16* hpc = hp + cp * 8;
    h8v acc = {};
    for (int it = 0; it < m; it += 4) {
        int i0 = se.x + it;
        int s0 = colidx[i0];
        int s1 = colidx[i0 + 1];
        int s2 = colidx[i0 + 2];
        int s3 = colidx[i0 + 3];
        s0 = (it < deg) ? s0 : N_NODES;
        s1 = (it + 1 < deg) ? s1 : N_NODES;
        s2 = (it + 2 < deg) ? s2 : N_NODES;
        s3 = (it + 3 < deg) ? s3 : N_NODES;
        h8v v0 = *(const h8v*)(hpc + (size_t)s0 * 64);
        h8v v1 = *(const h8v*)(hpc + (size_t)s1 * 64);
        h8v v2 = *(const h8v*)(hpc + (size_t)s2 * 64);
        h8v v3 = *(const h8v*)(hpc + (size_t)s3 * 64);
        acc += v0;
        acc += v1;
        acc += v2;
        acc += v3;
    }

    h8v sv = *(const h8v*)(hpc + (size_t)r * 64);  // self-loop
    float dv = rsqrtf((float)(deg + 1));
    float z[8];
#pragma unroll
    for (int j = 0; j < 8; j++) z[j] = dv * ((float)acc[j] + (float)sv[j]);

    const bool act = cp < 5;  // cols 0..39
    float pm = -INFINITY;
    if (act) {
#pragma unroll
        for (int j = 0; j < 8; j++) pm = fmaxf(pm, z[j]);
    }
    pm = fmaxf(pm, __shfl_xor(pm, 1));
    pm = fmaxf(pm, __shfl_xor(pm, 2));
    pm = fmaxf(pm, __shfl_xor(pm, 4));
    float pe = 0.f;
    if (act) {
#pragma unroll
        for (int j = 0; j < 8; j++) pe += __expf(z[j] - pm);
    }
    pe += __shfl_xor(pe, 1);
    pe += __shfl_xor(pe, 2);
    pe += __shfl_xor(pe, 4);
    float lse = __logf(pe);
    if (act) {
        float* po = out + (size_t)r * 40 + cp * 8;
        float4 o0 = make_float4(z[0] - pm - lse, z[1] - pm - lse, z[2] - pm - lse, z[3] - pm - lse);
        float4 o1 = make_float4(z[4] - pm - lse, z[5] - pm - lse, z[6] - pm - lse, z[7] - pm - lse);
        *(float4*)po = o0;
        *(float4*)(po + 4) = o1;
    }
}

// ---------------- launch ----------------

extern "C" void kernel_launch(void* const* d_in, const int* in_sizes, int n_in,
                              void* d_out, int out_size, void* d_ws, size_t ws_size,
                              hipStream_t stream) {
    const float* x     = (const float*)d_in[0];
    const int*   ei    = (const int*)d_in[1];
    const float* W_in  = (const float*)d_in[2];
    const float* b_in  = (const float*)d_in[3];
    const float* W_mid = (const float*)d_in[4];
    const float* b_mid = (const float*)d_in[5];
    const float* W_out = (const float*)d_in[6];
    float* out = (float*)d_out;

    const int* srcv = ei;
    const int* dstv = ei + N_EDGES;

    char* w = (char*)d_ws;
    float* dinv   = (float*)(w);                              // 400 KB
    i32x2* rowse  = (i32x2*)(w + (1ull << 19));               // 800 KB
    int* bcnt     = (int*)(w + 1507328);                      // 2 KB
    int* colidx   = (int*)(w + (2ull << 20));                 // 7.2 MB + pad
    unsigned int* ebuf = (unsigned int*)(w + (10ull << 20));  // 7.2 MB
    _Float16* Wt  = (_Float16*)(w + (18ull << 20));           // 155 KB
    _Float16* bufA = (_Float16*)(w + (19ull << 20));          // (N+1)*128 fp16
    _Float16* bufB = (_Float16*)(w + (45ull << 20));          // (N+1)*128 fp16
    _Float16* zbuf = (_Float16*)(w + (71ull << 20));          // (N+1)*64 fp16

    _Float16* W2h = Wt + 2 * 128 * 128;
    _Float16* W2l = Wt + 3 * 128 * 128;
    _Float16* W3h = Wt + 4 * 128 * 128;
    _Float16* W3l = Wt + 4 * 128 * 128 + 48 * 128;

    // bcnt zero (queue op), then bpart + wprep + sentinels in one launch
    (void)hipMemsetAsync(bcnt, 0, NBUCK * sizeof(int), stream);
    k_bpart<<<480, 256, 0, stream>>>(srcv, dstv, bcnt, ebuf, W_mid, W_out, Wt,
                                     bufA, bufB, zbuf);
    // CSR finalize + block-local L1 GEMM (bufA = g1 = dinv * (x @ W1))
    k_bucket<<<NBUCK, 256, 0, stream>>>(ebuf, bcnt, rowse, dinv, colidx, x, W_in, bufA);
    // Layer 1 agg + Layer 2 GEMM fused: gather g1 -> relu(+b_in) -> @W2 -> *dinv -> bufB (g2)
    k_fused128<<<N_NODES / 16, 256, 0, stream>>>(bufA, rowse, colidx, b_in, dinv, W2h, W2l, bufB);
    // Layer 2 agg + Layer 3 GEMM fused: gather g2 -> relu(+b_mid) -> @W3 -> *dinv -> zbuf (g3)
    k_fused40<<<N_NODES / 16, 256, 0, stream>>>(bufB, rowse, colidx, b_mid, dinv, W3h, W3l, zbuf);
    // Final aggregation + log_softmax
    k_agg_out<<<N_NODES / 32, 256, 0, stream>>>(zbuf, rowse, colidx, out);
}

// Round 12
// 350.465 us; speedup vs baseline: 1.0235x; 1.0235x over previous
//
#include <hip/hip_runtime.h>
#include <math.h>

#define N_NODES 100000
#define N_EDGES 1600000
#define NBUCK 391          // ceil(100000 / 256)
#define BSTRIDE 4608       // bucket slack stride: mean 4096 + 8 sigma

typedef __attribute__((ext_vector_type(8))) _Float16 h8v;
typedef __attribute__((ext_vector_type(4))) float f32x4;
typedef __attribute__((ext_vector_type(2))) int i32x2;

#define GEMM_GRID 625
#define NTILES 3125

// ---------------- bpart + misc tail ----------------
// Blocks 0..390: edge partition into 391 dst-buckets (round-0 proven form).
// Blocks 391..478: weight prep for W2 (128 cols) + W3 (48, zero-padded).
// Block 479: zero sentinel rows of bufA/bufB/zbuf.
// (bcnt zeroed by hipMemsetAsync before this launch.)

__launch_bounds__(256)
__global__ void k_bpart(const int* __restrict__ srcv, const int* __restrict__ dstv,
                        int* __restrict__ bcnt, unsigned int* __restrict__ ebuf,
                        const float* __restrict__ W2, const float* __restrict__ W3,
                        _Float16* __restrict__ Wt,
                        _Float16* __restrict__ bufA, _Float16* __restrict__ bufB,
                        _Float16* __restrict__ zbuf) {
    const int tid = threadIdx.x;
    const int bid = blockIdx.x;

    if (bid >= 391) {
        if (bid == 479) {
            if (tid < 128) {
                bufA[(size_t)N_NODES * 128 + tid] = (_Float16)0.f;
                bufB[(size_t)N_NODES * 128 + tid] = (_Float16)0.f;
            }
            if (tid < 64)  zbuf[(size_t)N_NODES * 64 + tid] = (_Float16)0.f;
            return;
        }
        // weight prep: 176*128 = 22528 elements over 88 blocks (exact)
        int idx = (bid - 391) * 256 + tid;
        if (idx >= 176 * 128) return;
        int n = idx / 128, k = idx % 128;
        _Float16 *ph, *pl;
        float v;
        if (n < 128) {
            v = W2[k * 128 + n];
            ph = Wt + 2 * 128 * 128; pl = Wt + 3 * 128 * 128;
        } else {
            int nloc = n - 128;
            v = (nloc < 40) ? W3[k * 40 + nloc] : 0.f;
            ph = Wt + 4 * 128 * 128; pl = Wt + 4 * 128 * 128 + 48 * 128;
            n = nloc;
        }
        _Float16 hi = (_Float16)v;
        _Float16 lo = (_Float16)(v - (float)hi);
        ph[n * 128 + k] = hi;
        pl[n * 128 + k] = lo;
        return;
    }

    // ---- bpart ----
    __shared__ int hist[NBUCK];
    __shared__ int cur[NBUCK];
    for (int t = tid; t < NBUCK; t += 256) hist[t] = 0;
    __syncthreads();
    const int base = bid * 4096;
#pragma unroll
    for (int i = 0; i < 16; i++) {
        int e = base + i * 256 + tid;
        if (e < N_EDGES) atomicAdd(&hist[dstv[e] >> 8], 1);
    }
    __syncthreads();
    for (int t = tid; t < NBUCK; t += 256)
        if (hist[t]) cur[t] = t * BSTRIDE + atomicAdd(&bcnt[t], hist[t]);
    __syncthreads();
#pragma unroll
    for (int i = 0; i < 16; i++) {
        int e = base + i * 256 + tid;
        if (e < N_EDGES) {
            int d = dstv[e];
            int p = atomicAdd(&cur[d >> 8], 1);
            ebuf[p] = ((unsigned int)srcv[e] << 8) | (unsigned int)(d & 255);
        }
    }
}

// ---------------- CSR finalize + block-local L1 GEMM (R11 verified form) ----------------

__launch_bounds__(256)
__global__ void k_bucket(const unsigned int* __restrict__ ebuf, const int* __restrict__ bcnt,
                         i32x2* __restrict__ rowse, float* __restrict__ dinv,
                         int* __restrict__ colidx,
                         const float* __restrict__ x, const float* __restrict__ W1,
                         _Float16* __restrict__ bufA) {
    __shared__ int cnt[256];
    __shared__ int s[256];
    __shared__ int cur[256];
    __shared__ float sdv[256];
    const int tid = threadIdx.x;
    const int b = blockIdx.x;
    const int e0 = b * BSTRIDE;
    const int e1 = e0 + bcnt[b];
    cnt[tid] = 0;
    __syncthreads();
    for (int e = e0 + tid; e < e1; e += 256) atomicAdd(&cnt[ebuf[e] & 255u], 1);
    __syncthreads();
    int v = cnt[tid];
    int x0 = v;
    s[tid] = x0;
    __syncthreads();
    for (int d = 1; d < 256; d <<= 1) {
        int t = (tid >= d) ? s[tid - d] : 0;
        __syncthreads();
        x0 += t;
        s[tid] = x0;
        __syncthreads();
    }
    int start = e0 + x0 - v;
    int node = b * 256 + tid;
    float dvv = rsqrtf((float)(v + 1));
    sdv[tid] = dvv;
    if (node < N_NODES) {
        i32x2 se;
        se.x = start;
        se.y = start + v;
        rowse[node] = se;
        dinv[node] = dvv;  // +1 self-loop (global copy for fused epilogues)
    }
    cur[tid] = start;
    __syncthreads();
    for (int e = e0 + tid; e < e1; e += 256) {
        unsigned int sd = ebuf[e];
        int pos = atomicAdd(&cur[sd & 255u], 1);
        colidx[pos] = (int)(sd >> 8);
    }

    // ---- block-local layer-1 GEMM: bufA[r] = dinv[r] * (x @ W1)[r] ----
    const int lane = tid & 63;
    const int wi = tid >> 6;
    const int nb = wi * 32;
    const int nn = lane & 15;
    const int quad = lane >> 4;
    const int kq = quad * 8;

    h8v bh[4][2], bl[4][2];
#pragma unroll
    for (int c = 0; c < 4; c++)
#pragma unroll
        for (int t = 0; t < 2; t++) {
#pragma unroll
            for (int j = 0; j < 8; j++) {
                float w = W1[(c * 32 + kq + j) * 128 + nb + t * 16 + nn];
                _Float16 hi = (_Float16)w;
                bh[c][t][j] = hi;
                bl[c][t][j] = (_Float16)(w - (float)hi);
            }
        }

#pragma unroll
    for (int tile = 0; tile < 8; tile++) {
        const int r0 = b * 256 + tile * 32;
        if (r0 >= N_NODES) break;
        f32x4 acc[2][2] = {};
#pragma unroll
        for (int c = 0; c < 4; c++) {
            h8v a[2];
#pragma unroll
            for (int m = 0; m < 2; m++) {
                int rl = r0 + m * 16 + nn;
                rl = (rl < N_NODES) ? rl : (N_NODES - 1);  // clamp OOB tail reads
                const float* p = x + (size_t)rl * 128 + c * 32 + kq;
                float4 p0 = *(const float4*)p;
                float4 p1 = *(const float4*)(p + 4);
                h8v av = {(_Float16)p0.x, (_Float16)p0.y, (_Float16)p0.z, (_Float16)p0.w,
                          (_Float16)p1.x, (_Float16)p1.y, (_Float16)p1.z, (_Float16)p1.w};
                a[m] = av;
            }
#pragma unroll
            for (int m = 0; m < 2; m++)
#pragma unroll
                for (int t = 0; t < 2; t++) {
                    acc[m][t] = __builtin_amdgcn_mfma_f32_16x16x32_f16(a[m], bh[c][t], acc[m][t], 0, 0, 0);
                    acc[m][t] = __builtin_amdgcn_mfma_f32_16x16x32_f16(a[m], bl[c][t], acc[m][t], 0, 0, 0);
                }
        }
#pragma unroll
        for (int m = 0; m < 2; m++)
#pragma unroll
            for (int reg = 0; reg < 4; reg++) {
                int r = r0 + m * 16 + quad * 4 + reg;
                if (r < N_NODES) {
                    float dv = sdv[r - b * 256];
#pragma unroll
                    for (int t = 0; t < 2; t++)
                        bufA[(size_t)r * 128 + nb + t * 16 + nn] = (_Float16)(acc[m][t][reg] * dv);
                }
            }
    }
}

// ---------------- Fused aggregation + GEMM, 32-row tiles (R5 measured-best form) ----------------
// Persistent B in VGPRs (loaded once), 2-pass gather per wave (rows wi*8+p*4+quad),
// __launch_bounds__(256,2). Measured 82.4 µs vs 90.6 for the 16-row variant.

__launch_bounds__(256, 2)
__global__ void k_fused128(const _Float16* __restrict__ hp, const i32x2* __restrict__ rowse,
                           const int* __restrict__ colidx, const float* __restrict__ bias,
                           const float* __restrict__ dinv,
                           const _Float16* __restrict__ Wthi, const _Float16* __restrict__ Wtlo,
                           _Float16* __restrict__ out) {
    __shared__ __align__(16) _Float16 As[32 * 128];
    const int lane = threadIdx.x & 63;
    const int wi = threadIdx.x >> 6;
    const int nn = lane & 15;
    const int quad = lane >> 4;
    const int kq = quad * 8;
    const int nb = wi * 32;

    h8v bh[4][2], bl[4][2];
#pragma unroll
    for (int c = 0; c < 4; c++)
#pragma unroll
        for (int t = 0; t < 2; t++) {
            int off = (nb + t * 16 + nn) * 128 + c * 32 + kq;
            bh[c][t] = *(const h8v*)(Wthi + off);
            bl[c][t] = *(const h8v*)(Wtlo + off);
        }

    const int r0 = blockIdx.x * 32;

    // ---- phase A: aggregate 32 rows (wave wi owns local rows wi*8 .. wi*8+7) ----
    const int rs = quad;
    const int cp = nn;
    const _Float16* hpc = hp + cp * 8;
    const float* bp = bias + cp * 8;
    float4 b0 = *(const float4*)bp;
    float4 b1 = *(const float4*)(bp + 4);
    float bb[8] = {b0.x, b0.y, b0.z, b0.w, b1.x, b1.y, b1.z, b1.w};
#pragma unroll
    for (int p = 0; p < 2; p++) {
        const int rl = wi * 8 + p * 4 + rs;
        const int r = r0 + rl;
        const i32x2 se = rowse[r];
        const int deg = se.y - se.x;
        int m = deg;
        m = max(m, __shfl_xor(m, 16));
        m = max(m, __shfl_xor(m, 32));
        h8v acc = {};
        for (int it = 0; it < m; it += 4) {
            int i0 = se.x + it;
            int s0 = colidx[i0];
            int s1 = colidx[i0 + 1];
            int s2 = colidx[i0 + 2];
            int s3 = colidx[i0 + 3];
            s0 = (it < deg) ? s0 : N_NODES;
            s1 = (it + 1 < deg) ? s1 : N_NODES;
            s2 = (it + 2 < deg) ? s2 : N_NODES;
            s3 = (it + 3 < deg) ? s3 : N_NODES;
            h8v v0 = *(const h8v*)(hpc + (size_t)s0 * 128);
            h8v v1 = *(const h8v*)(hpc + (size_t)s1 * 128);
            h8v v2 = *(const h8v*)(hpc + (size_t)s2 * 128);
            h8v v3 = *(const h8v*)(hpc + (size_t)s3 * 128);
            acc += v0;
            acc += v1;
            acc += v2;
            acc += v3;
        }
        h8v sv = *(const h8v*)(hpc + (size_t)r * 128);  // self-loop (g[r])
        float dv = rsqrtf((float)(deg + 1));
        h8v o;
#pragma unroll
        for (int j = 0; j < 8; j++) {
            float sx = (float)acc[j] + (float)sv[j];
            o[j] = (_Float16)fmaxf(fmaf(dv, sx, bb[j]), 0.f);
        }
        *(h8v*)(As + rl * 128 + ((cp ^ (rl & 15)) * 8)) = o;
    }
    __syncthreads();

    // ---- phase B: 32x128 tile @ W (this wave's 32 cols), out *= dinv[r] ----
    f32x4 acc2[2][2] = {};
#pragma unroll
    for (int c = 0; c < 4; c++) {
        h8v a[2];
#pragma unroll
        for (int mm = 0; mm < 2; mm++) {
            int R = mm * 16 + nn;
            int ch = (c * 4 + quad) ^ (R & 15);
            a[mm] = *(const h8v*)(As + R * 128 + ch * 8);
        }
#pragma unroll
        for (int mm = 0; mm < 2; mm++)
#pragma unroll
            for (int t = 0; t < 2; t++) {
                acc2[mm][t] = __builtin_amdgcn_mfma_f32_16x16x32_f16(a[mm], bh[c][t], acc2[mm][t], 0, 0, 0);
                acc2[mm][t] = __builtin_amdgcn_mfma_f32_16x16x32_f16(a[mm], bl[c][t], acc2[mm][t], 0, 0, 0);
            }
    }
#pragma unroll
    for (int mm = 0; mm < 2; mm++)
#pragma unroll
        for (int reg = 0; reg < 4; reg++) {
            int r = r0 + mm * 16 + quad * 4 + reg;
            float dr = dinv[r];
#pragma unroll
            for (int t = 0; t < 2; t++)
                out[(size_t)r * 128 + nb + t * 16 + nn] = (_Float16)(acc2[mm][t][reg] * dr);
        }
}

// Fused aggregation + layer-3 GEMM (48 cols) into [N+1][64]-stride buffer.
// R5 measured-best form: 32-row tiles, persistent B, waves 0..2 in phase B.
__launch_bounds__(256, 2)
__global__ void k_fused40(const _Float16* __restrict__ hp, const i32x2* __restrict__ rowse,
                          const int* __restrict__ colidx, const float* __restrict__ bias,
                          const float* __restrict__ dinv,
                          const _Float16* __restrict__ Wthi, const _Float16* __restrict__ Wtlo,
                          _Float16* __restrict__ out) {
    __shared__ __align__(16) _Float16 As[32 * 128];
    const int lane = threadIdx.x & 63;
    const int wi = threadIdx.x >> 6;
    const int nn = lane & 15;
    const int quad = lane >> 4;
    const int kq = quad * 8;

    h8v bh[4], bl[4];
    if (wi < 3) {
#pragma unroll
        for (int c = 0; c < 4; c++) {
            int off = (wi * 16 + nn) * 128 + c * 32 + kq;
            bh[c] = *(const h8v*)(Wthi + off);
            bl[c] = *(const h8v*)(Wtlo + off);
        }
    }

    const int r0 = blockIdx.x * 32;

    // ---- phase A ----
    const int rs = quad;
    const int cp = nn;
    const _Float16* hpc = hp + cp * 8;
    const float* bp = bias + cp * 8;
    float4 b0 = *(const float4*)bp;
    float4 b1 = *(const float4*)(bp + 4);
    float bb[8] = {b0.x, b0.y, b0.z, b0.w, b1.x, b1.y, b1.z, b1.w};
#pragma unroll
    for (int p = 0; p < 2; p++) {
        const int rl = wi * 8 + p * 4 + rs;
        const int r = r0 + rl;
        const i32x2 se = rowse[r];
        const int deg = se.y - se.x;
        int m = deg;
        m = max(m, __shfl_xor(m, 16));
        m = max(m, __shfl_xor(m, 32));
        h8v acc = {};
        for (int it = 0; it < m; it += 4) {
            int i0 = se.x + it;
            int s0 = colidx[i0];
            int s1 = colidx[i0 + 1];
            int s2 = colidx[i0 + 2];
            int s3 = colidx[i0 + 3];
            s0 = (it < deg) ? s0 : N_NODES;
            s1 = (it + 1 < deg) ? s1 : N_NODES;
            s2 = (it + 2 < deg) ? s2 : N_NODES;
            s3 = (it + 3 < deg) ? s3 : N_NODES;
            h8v v0 = *(const h8v*)(hpc + (size_t)s0 * 128);
            h8v v1 = *(const h8v*)(hpc + (size_t)s1 * 128);
            h8v v2 = *(const h8v*)(hpc + (size_t)s2 * 128);
            h8v v3 = *(const h8v*)(hpc + (size_t)s3 * 128);
            acc += v0;
            acc += v1;
            acc += v2;
            acc += v3;
        }
        h8v sv = *(const h8v*)(hpc + (size_t)r * 128);  // self-loop (g[r])
        float dv = rsqrtf((float)(deg + 1));
        h8v o;
#pragma unroll
        for (int j = 0; j < 8; j++) {
            float sx = (float)acc[j] + (float)sv[j];
            o[j] = (_Float16)fmaxf(fmaf(dv, sx, bb[j]), 0.f);
        }
        *(h8v*)(As + rl * 128 + ((cp ^ (rl & 15)) * 8)) = o;
    }
    __syncthreads();

    // ---- phase B: 32x128 tile @ W3 (waves 0..2 -> cols wi*16..+15), out *= dinv[r] ----
    if (wi < 3) {
        f32x4 acc2[2] = {};
#pragma unroll
        for (int c = 0; c < 4; c++) {
            h8v a[2];
#pragma unroll
            for (int mm = 0; mm < 2; mm++) {
                int R = mm * 16 + nn;
                int ch = (c * 4 + quad) ^ (R & 15);
                a[mm] = *(const h8v*)(As + R * 128 + ch * 8);
            }
#pragma unroll
            for (int mm = 0; mm < 2; mm++) {
                acc2[mm] = __builtin_amdgcn_mfma_f32_16x16x32_f16(a[mm], bh[c], acc2[mm], 0, 0, 0);
                acc2[mm] = __builtin_amdgcn_mfma_f32_16x16x32_f16(a[mm], bl[c], acc2[mm], 0, 0, 0);
            }
        }
#pragma unroll
        for (int mm = 0; mm < 2; mm++)
#pragma unroll
            for (int reg = 0; reg < 4; reg++) {
                int r = r0 + mm * 16 + quad * 4 + reg;
                float dr = dinv[r];
                out[(size_t)r * 64 + wi * 16 + nn] = (_Float16)(acc2[mm][reg] * dr);
            }
    }
}

// ---------------- Final aggregation (64-stride rows) + fused log_softmax ----------------

__launch_bounds__(256)
__global__ void k_agg_out(const _Float16* __restrict__ hp, const i32x2* __restrict__ rowse,
                          const int* __restrict__ colidx, float* __restrict__ out) {
    const int lane = threadIdx.x & 63;
    const int wid = (blockIdx.x * blockDim.x + threadIdx.x) >> 6;
    const int rs = lane >> 3;   // row slot 0..7
    const int cp = lane & 7;    // 16B col part
    const int r = wid * 8 + rs;

    const i32x2 se = rowse[r];
    const int deg = se.y - se.x;
    int m = deg;
    m = max(m, __shfl_xor(m, 8));
    m = max(m, __shfl_xor(m, 16));
    m = max(m, __shfl_xor(m, 32));

    const _Float16* hpc = hp + cp * 8;
    h8v acc = {};
    for (int it = 0; it < m; it += 4) {
        int i0 = se.x + it;
        int s0 = colidx[i0];
        int s1 = colidx[i0 + 1];
        int s2 = colidx[i0 + 2];
        int s3 = colidx[i0 + 3];
        s0 = (it < deg) ? s0 : N_NODES;
        s1 = (it + 1 < deg) ? s1 : N_NODES;
        s2 = (it + 2 < deg) ? s2 : N_NODES;
        s3 = (it + 3 < deg) ? s3 : N_NODES;
        h8v v0 = *(const h8v*)(hpc + (size_t)s0 * 64);
        h8v v1 = *(const h8v*)(hpc + (size_t)s1 * 64);
        h8v v2 = *(const h8v*)(hpc + (size_t)s2 * 64);
        h8v v3 = *(const h8v*)(hpc + (size_t)s3 * 64);
        acc += v0;
        acc += v1;
        acc += v2;
        acc += v3;
    }

    h8v sv = *(const h8v*)(hpc + (size_t)r * 64);  // self-loop
    float dv = rsqrtf((float)(deg + 1));
    float z[8];
#pragma unroll
    for (int j = 0; j < 8; j++) z[j] = dv * ((float)acc[j] + (float)sv[j]);

    const bool act = cp < 5;  // cols 0..39
    float pm = -INFINITY;
    if (act) {
#pragma unroll
        for (int j = 0; j < 8; j++) pm = fmaxf(pm, z[j]);
    }
    pm = fmaxf(pm, __shfl_xor(pm, 1));
    pm = fmaxf(pm, __shfl_xor(pm, 2));
    pm = fmaxf(pm, __shfl_xor(pm, 4));
    float pe = 0.f;
    if (act) {
#pragma unroll
        for (int j = 0; j < 8; j++) pe += __expf(z[j] - pm);
    }
    pe += __shfl_xor(pe, 1);
    pe += __shfl_xor(pe, 2);
    pe += __shfl_xor(pe, 4);
    float lse = __logf(pe);
    if (act) {
        float* po = out + (size_t)r * 40 + cp * 8;
        float4 o0 = make_float4(z[0] - pm - lse, z[1] - pm - lse, z[2] - pm - lse, z[3] - pm - lse);
        float4 o1 = make_float4(z[4] - pm - lse, z[5] - pm - lse, z[6] - pm - lse, z[7] - pm - lse);
        *(float4*)po = o0;
        *(float4*)(po + 4) = o1;
    }
}

// ---------------- launch ----------------

extern "C" void kernel_launch(void* const* d_in, const int* in_sizes, int n_in,
                              void* d_out, int out_size, void* d_ws, size_t ws_size,
                              hipStream_t stream) {
    const float* x     = (const float*)d_in[0];
    const int*   ei    = (const int*)d_in[1];
    const float* W_in  = (const float*)d_in[2];
    const float* b_in  = (const float*)d_in[3];
    const float* W_mid = (const float*)d_in[4];
    const float* b_mid = (const float*)d_in[5];
    const float* W_out = (const float*)d_in[6];
    float* out = (float*)d_out;

    const int* srcv = ei;
    const int* dstv = ei + N_EDGES;

    char* w = (char*)d_ws;
    float* dinv   = (float*)(w);                              // 400 KB
    i32x2* rowse  = (i32x2*)(w + (1ull << 19));               // 800 KB
    int* bcnt     = (int*)(w + 1507328);                      // 2 KB
    int* colidx   = (int*)(w + (2ull << 20));                 // 7.2 MB + pad
    unsigned int* ebuf = (unsigned int*)(w + (10ull << 20));  // 7.2 MB
    _Float16* Wt  = (_Float16*)(w + (18ull << 20));           // 155 KB
    _Float16* bufA = (_Float16*)(w + (19ull << 20));          // (N+1)*128 fp16
    _Float16* bufB = (_Float16*)(w + (45ull << 20));          // (N+1)*128 fp16
    _Float16* zbuf = (_Float16*)(w + (71ull << 20));          // (N+1)*64 fp16

    _Float16* W2h = Wt + 2 * 128 * 128;
    _Float16* W2l = Wt + 3 * 128 * 128;
    _Float16* W3h = Wt + 4 * 128 * 128;
    _Float16* W3l = Wt + 4 * 128 * 128 + 48 * 128;

    // bcnt zero (queue op), then bpart + wprep + sentinels in one launch
    (void)hipMemsetAsync(bcnt, 0, NBUCK * sizeof(int), stream);
    k_bpart<<<480, 256, 0, stream>>>(srcv, dstv, bcnt, ebuf, W_mid, W_out, Wt,
                                     bufA, bufB, zbuf);
    // CSR finalize + block-local L1 GEMM (bufA = g1 = dinv * (x @ W1))
    k_bucket<<<NBUCK, 256, 0, stream>>>(ebuf, bcnt, rowse, dinv, colidx, x, W_in, bufA);
    // Layer 1 agg + Layer 2 GEMM fused (R5 32-row form): g1 -> relu(+b_in) -> @W2 -> *dinv -> bufB
    k_fused128<<<NTILES, 256, 0, stream>>>(bufA, rowse, colidx, b_in, dinv, W2h, W2l, bufB);
    // Layer 2 agg + Layer 3 GEMM fused (R5 32-row form): g2 -> relu(+b_mid) -> @W3 -> *dinv -> zbuf
    k_fused40<<<NTILES, 256, 0, stream>>>(bufB, rowse, colidx, b_mid, dinv, W3h, W3l, zbuf);
    // Final aggregation + log_softmax
    k_agg_out<<<N_NODES / 32, 256, 0, stream>>>(zbuf, rowse, colidx, out);
}